// Round 13
// baseline (7406.371 us; speedup 1.0000x reference)
//
#include <hip/hip_runtime.h>
#include <hip/hip_bf16.h>

#define Tn 1024
#define Bn 128
#define INn 32
#define Hn 512
#define OUTn 32
#define Kn 64

typedef __attribute__((ext_vector_type(8))) __bf16 bf16x8;
typedef __attribute__((ext_vector_type(4))) float f32x4;
typedef __attribute__((ext_vector_type(4))) unsigned int u32x4;
typedef __attribute__((ext_vector_type(2))) unsigned int u32x2;

typedef const __attribute__((address_space(1))) void* gas_p;
typedef __attribute__((address_space(3))) void* las_p;

static __device__ __forceinline__ float bf2f(unsigned short u) {
    union { unsigned int i; float f; } c; c.i = ((unsigned int)u) << 16; return c.f;
}
static __device__ __forceinline__ unsigned short f2bf(float f) {
    union { float f; unsigned int i; } c; c.f = f;
    unsigned int x = c.i;
    return (unsigned short)((x + 0x7fffu + ((x >> 16) & 1u)) >> 16);
}
static __device__ __forceinline__ float tanh_fast(float x) {
    float xc = fminf(fmaxf(x, -10.f), 10.f);
    float e = __expf(2.f * xc);
    return (e - 1.f) * __builtin_amdgcn_rcpf(e + 1.f);
}

// ---------------- f32 -> bf16 convert (n divisible by 4) ----------------
__global__ __launch_bounds__(256) void cvt_k(const float* __restrict__ in,
                                             unsigned short* __restrict__ out, int n4) {
    int i = blockIdx.x * 256 + threadIdx.x;
    if (i < n4) {
        float4 v = ((const float4*)in)[i];
        ushort4 o;
        o.x = f2bf(v.x); o.y = f2bf(v.y); o.z = f2bf(v.z); o.w = f2bf(v.w);
        ((ushort4*)out)[i] = o;
    }
}

// ---------------- pi coefficients + combined biases ----------------
__global__ __launch_bounds__(512) void prep_small(const float* __restrict__ b_d,
                                                  const float* __restrict__ bih0, const float* __restrict__ bhh0,
                                                  const float* __restrict__ bih1, const float* __restrict__ bhh1,
                                                  float* __restrict__ pi, float* __restrict__ bias0,
                                                  float* __restrict__ bias1) {
    int i = threadIdx.x;
    float d = 0.5f / (1.0f + expf(-b_d[i]));
    float c = 1.0f;
    for (int j = 1; j <= Kn; ++j) {
        c *= ((float)(j - 1) - d) / (float)j;
        pi[(j - 1) * Hn + i] = c;
    }
    bias0[i] = bih0[i] + bhh0[i];
    bias1[i] = bih1[i] + bhh1[i];
}

// ---------------- GEMM: C[M,N](bf16) = A[M,K](bf16) . Bm[N,K](bf16)^T + bias[N](f32) --------
__global__ __launch_bounds__(256, 2) void gemm_bt(const unsigned short* __restrict__ A,
                                                  const unsigned short* __restrict__ Bm,
                                                  unsigned short* __restrict__ C,
                                                  const float* __restrict__ bias,
                                                  int M, int N, int K) {
    __shared__ unsigned short As[128 * 32];
    __shared__ unsigned short Bs[128 * 32];
    int ntile = N >> 7;
    int bm = blockIdx.x / ntile;
    int bn = blockIdx.x - bm * ntile;
    size_t m0 = (size_t)bm << 7;
    int n0 = bn << 7;
    int tid = threadIdx.x;
    int lane = tid & 63, w = tid >> 6;
    int wm = w >> 1, wn = w & 1;
    int r = lane & 15, g = lane >> 4;
    int srow = tid >> 2, sblk = tid & 3;
    f32x4 acc[4][4] = {};
    for (int k0 = 0; k0 < K; k0 += 32) {
#pragma unroll
        for (int it = 0; it < 2; ++it) {
            const unsigned short* ga = A + (m0 + it * 64 + srow) * (size_t)K + k0 + sblk * 8;
            __builtin_amdgcn_global_load_lds((gas_p)ga, (las_p)((char*)As + it * 4096 + w * 1024), 16, 0, 0);
            const unsigned short* gbp = Bm + ((size_t)(n0 + it * 64 + srow)) * (size_t)K + k0 + sblk * 8;
            __builtin_amdgcn_global_load_lds((gas_p)gbp, (las_p)((char*)Bs + it * 4096 + w * 1024), 16, 0, 0);
        }
        __syncthreads();
        bf16x8 af[4], bfr[4];
#pragma unroll
        for (int m = 0; m < 4; ++m) af[m] = *(const bf16x8*)&As[(wm * 64 + m * 16 + r) * 32 + g * 8];
#pragma unroll
        for (int n = 0; n < 4; ++n) bfr[n] = *(const bf16x8*)&Bs[(wn * 64 + n * 16 + r) * 32 + g * 8];
#pragma unroll
        for (int m = 0; m < 4; ++m)
#pragma unroll
            for (int n = 0; n < 4; ++n)
                acc[m][n] = __builtin_amdgcn_mfma_f32_16x16x32_bf16(af[m], bfr[n], acc[m][n], 0, 0, 0);
        __syncthreads();
    }
#pragma unroll
    for (int n = 0; n < 4; ++n) {
        int col = n0 + wn * 64 + n * 16 + r;
        float bv = bias[col];
#pragma unroll
        for (int m = 0; m < 4; ++m) {
            size_t row0 = m0 + wm * 64 + m * 16 + g * 4;
#pragma unroll
            for (int q = 0; q < 4; ++q)
                C[(row0 + q) * (size_t)N + col] = f2bf(acc[m][n][q] + bv);
        }
    }
}

// ---------------- causal fractional-diff filter (chunked over t) ----------------
__global__ __launch_bounds__(256, 2) void filt_k(const unsigned short* __restrict__ X,
                                                 const float* __restrict__ Pi,
                                                 unsigned short* __restrict__ Y, int t_off) {
    int tid = threadIdx.x;
    int il = tid & 63, ts = tid >> 6;
    int i = blockIdx.x * 64 + il;
    int b = blockIdx.z;
    int tbase = t_off + blockIdx.y * 128 + ts * 32;
    float xr[96];
#pragma unroll
    for (int k2 = 0; k2 < 96; ++k2) {
        int t = tbase - 64 + k2;
        xr[k2] = (t >= 0) ? bf2f(X[(size_t)t * (Bn * Hn) + b * Hn + i]) : 0.0f;
    }
    float acc[32];
#pragma unroll
    for (int tt = 0; tt < 32; ++tt) acc[tt] = xr[64 + tt];
#pragma unroll
    for (int j = 1; j <= 64; ++j) {
        float p = Pi[(j - 1) * Hn + i];
#pragma unroll
        for (int tt = 0; tt < 32; ++tt) acc[tt] += p * xr[64 + tt - j];
    }
#pragma unroll
    for (int tt = 0; tt < 32; ++tt)
        Y[(size_t)(tbase - t_off + tt) * (Bn * Hn) + b * Hn + i] = f2bf(acc[tt]);
}

// ---------------- recurrence v15: W in LDS (XOR-swizzled), 64 wgs, tag-in-data -------------
// 64 wgs = 8 gb (16-batch groups) x 8 og (64-o eighths); bid = gb + 8*og -> all 8 partners
// of a gb share an XCD under round-robin (perf heuristic only). 256 thr = 4 waves; wave w
// owns o-rows [og*64 + w*16, +16). W slice [64][512] staged ONCE to LDS via global_load_lds
// with PRE-SWIZZLED per-lane source (linear dest): LDS chunk c of row holds W chunk
// c^(row&7). Reads XOR identically -> bank-arithmetic-verified 8 dwords/bank (optimal) for
// W-reads, h-reads, AND scatter writes (rec4's 92M conflicts -> ~0). No W register array
// anywhere (the allocator remats big arrays to L2/scratch -- proven rounds 4/6/9/10/12).
// Step: issue 8 tagged polls (sc1) -> preload 16 W-frags from LDS (hides poll RT) ->
// tied vmcnt(0) wait + tag check (+s_sleep retry) -> scatter 4x b128 (swizzled) ->
// [lgkm barrier] -> 16 MFMA in 2 chains (even/odd kk) -> tanh x4 -> publish 1 tagged
// dwordx4 -> hs store -> prefetch pre[t+2].
// ex: u32[2 par][8 gb][16 b][512 o], val = (bf16<<16)|(fbase+t+1). Overwrite safety: a wg
// publishes V only after consuming all partners' V-1, which they published only after
// consuming V-2 -> the slot being overwritten is globally dead. memset per launch.
__global__ __launch_bounds__(256, 1) void rec15_k(const unsigned short* __restrict__ W,
                                                  const unsigned short* pre,
                                                  unsigned short* hs,
                                                  float* __restrict__ hfin,
                                                  unsigned int* ex, int fbase) {
    __shared__ unsigned short Wl[64 * 512];
    __shared__ unsigned short hl[2][16][512];
    int bid = blockIdx.x;
    int gb = bid & 7, og = bid >> 3;
    int tid = threadIdx.x, lane = tid & 63, w = tid >> 6;
    int r = lane & 15, g = lane >> 4;
    int rx = r & 7;
    // stage W rows [og*64, og*64+64): linear LDS dest, pre-swizzled global source
#pragma unroll
    for (int it = 0; it < 16; ++it) {
        int row = it * 4 + w;
        const unsigned short* gsrc = W + (size_t)(og * 64 + row) * Hn + (size_t)((lane ^ (row & 7)) * 8);
        __builtin_amdgcn_global_load_lds((gas_p)gsrc, (las_p)((char*)Wl + row * 1024), 16, 0, 0);
    }
    int bb = gb * 16 + r;
    const unsigned short* preP = pre + (size_t)bb * Hn + og * 64 + w * 16 + g * 4;
    unsigned short* hsP = hs ? hs + (size_t)bb * Hn + og * 64 + w * 16 + g * 4 : (unsigned short*)0;
    int pb = tid >> 4;                       // poll: batch row 0..15
    int pc = (tid & 15) * 4;                 // poll: first 8-value chunk (covers chunks pc..pc+3)
    const unsigned int* exRd = ex + (size_t)gb * 8192 + pb * 512 + pc * 8;
    unsigned int* exWr = ex + (size_t)gb * 8192 + r * 512 + og * 64 + w * 16 + g * 4;
    unsigned long long pfA = *(const unsigned long long*)(preP);
    unsigned long long pfB = *(const unsigned long long*)(preP + (size_t)(Bn * Hn));
    __syncthreads();                         // W staged (vmcnt drained by barrier semantics)

#define CHK4(V) ((V.x & 0xffffu) == tg && (V.y & 0xffffu) == tg && \
                 (V.z & 0xffffu) == tg && (V.w & 0xffffu) == tg)
#define PACK2(E, O) (((E) >> 16) | ((O) & 0xffff0000u))
#define POLL8(CON)                                                                            \
    asm volatile("global_load_dwordx4 %0, %8, off sc1\n\t"                                    \
                 "global_load_dwordx4 %1, %8, off offset:16 sc1\n\t"                          \
                 "global_load_dwordx4 %2, %8, off offset:32 sc1\n\t"                          \
                 "global_load_dwordx4 %3, %8, off offset:48 sc1\n\t"                          \
                 "global_load_dwordx4 %4, %8, off offset:64 sc1\n\t"                          \
                 "global_load_dwordx4 %5, %8, off offset:80 sc1\n\t"                          \
                 "global_load_dwordx4 %6, %8, off offset:96 sc1\n\t"                          \
                 "global_load_dwordx4 %7, %8, off offset:112 sc1" CON                         \
                 : "=v"(a0), "=v"(a1), "=v"(a2), "=v"(a3),                                    \
                   "=v"(a4), "=v"(a5), "=v"(a6), "=v"(a7) : "v"(rp) : "memory")

#define REC_STEP(TT, PF, ISLAST)                                                                 \
    {                                                                                            \
        const int p = TT & 1;                                                                    \
        unsigned tg = (unsigned)(fbase + TT);                                                    \
        u32x4 a0, a1, a2, a3, a4, a5, a6, a7;                                                    \
        const unsigned int* rp = exRd + (size_t)p * 65536;                                       \
        if (TT > 0) { POLL8(); }   /* issue early: RT hides under W-frag preloads */             \
        bf16x8 wf[16];                                                                           \
        _Pragma("unroll") for (int kk = 0; kk < 16; ++kk)                                        \
            wf[kk] = *(const bf16x8*)&Wl[(w * 16 + r) * 512 + (((kk * 4 + g) ^ rx) << 3)];       \
        if (TT > 0) {                                                                            \
            asm volatile("s_waitcnt vmcnt(0)"                                                    \
                         : "+v"(a0), "+v"(a1), "+v"(a2), "+v"(a3),                               \
                           "+v"(a4), "+v"(a5), "+v"(a6), "+v"(a7) :: "memory");                  \
            while (!(CHK4(a0) && CHK4(a1) && CHK4(a2) && CHK4(a3) &&                             \
                     CHK4(a4) && CHK4(a5) && CHK4(a6) && CHK4(a7))) {                            \
                __builtin_amdgcn_s_sleep(1);                                                     \
                POLL8("\n\ts_waitcnt vmcnt(0)");                                                 \
            }                                                                                    \
            u32x4 w0 = { PACK2(a0.x, a0.y), PACK2(a0.z, a0.w), PACK2(a1.x, a1.y), PACK2(a1.z, a1.w) }; \
            u32x4 w1 = { PACK2(a2.x, a2.y), PACK2(a2.z, a2.w), PACK2(a3.x, a3.y), PACK2(a3.z, a3.w) }; \
            u32x4 w2 = { PACK2(a4.x, a4.y), PACK2(a4.z, a4.w), PACK2(a5.x, a5.y), PACK2(a5.z, a5.w) }; \
            u32x4 w3 = { PACK2(a6.x, a6.y), PACK2(a6.z, a6.w), PACK2(a7.x, a7.y), PACK2(a7.z, a7.w) }; \
            *(u32x4*)&hl[p][pb][(((pc + 0) ^ (pb & 7)) << 3)] = w0;                              \
            *(u32x4*)&hl[p][pb][(((pc + 1) ^ (pb & 7)) << 3)] = w1;                              \
            *(u32x4*)&hl[p][pb][(((pc + 2) ^ (pb & 7)) << 3)] = w2;                              \
            *(u32x4*)&hl[p][pb][(((pc + 3) ^ (pb & 7)) << 3)] = w3;                              \
        }                                                                                        \
        asm volatile("s_waitcnt lgkmcnt(0)\n\ts_barrier" ::: "memory");  /* h(t) in hl[p] */     \
        f32x4 accE = {0.f, 0.f, 0.f, 0.f}, accO = {0.f, 0.f, 0.f, 0.f};                          \
        if (TT > 0) {                                                                            \
            _Pragma("unroll") for (int kk = 0; kk < 16; kk += 2) {                               \
                bf16x8 hbE = *(const bf16x8*)&hl[p][r][(((kk * 4 + g) ^ rx) << 3)];              \
                bf16x8 hbO = *(const bf16x8*)&hl[p][r][((((kk + 1) * 4 + g) ^ rx) << 3)];        \
                accE = __builtin_amdgcn_mfma_f32_16x16x32_bf16(wf[kk], hbE, accE, 0, 0, 0);      \
                accO = __builtin_amdgcn_mfma_f32_16x16x32_bf16(wf[kk + 1], hbO, accO, 0, 0, 0);  \
            }                                                                                    \
        }                                                                                        \
        union { unsigned long long u; unsigned short s[4]; } q; q.u = PF;                        \
        float h0 = tanh_fast(accE[0] + accO[0] + bf2f(q.s[0]));                                  \
        float h1 = tanh_fast(accE[1] + accO[1] + bf2f(q.s[1]));                                  \
        float h2 = tanh_fast(accE[2] + accO[2] + bf2f(q.s[2]));                                  \
        float h3 = tanh_fast(accE[3] + accO[3] + bf2f(q.s[3]));                                  \
        unsigned int b0 = f2bf(h0), b1 = f2bf(h1), b2 = f2bf(h2), b3 = f2bf(h3);                 \
        unsigned tv = tg + 1u;                                                                   \
        u32x4 s0 = { (b0 << 16) | tv, (b1 << 16) | tv, (b2 << 16) | tv, (b3 << 16) | tv };       \
        unsigned int* wp = exWr + (size_t)((TT + 1) & 1) * 65536;                                \
        asm volatile("global_store_dwordx4 %0, %1, off sc1" :: "v"(wp), "v"(s0) : "memory");     \
        if (hsP) {                                                                               \
            union { unsigned int u[2]; unsigned long long v; } o;                                \
            o.u[0] = b0 | (b1 << 16); o.u[1] = b2 | (b3 << 16);                                  \
            *(unsigned long long*)(hsP + (size_t)TT * (Bn * Hn)) = o.v;                          \
        }                                                                                        \
        if (ISLAST && hfin) {                                                                    \
            float* hf = hfin + (size_t)bb * Hn + og * 64 + w * 16 + g * 4;                       \
            hf[0] = h0; hf[1] = h1; hf[2] = h2; hf[3] = h3;                                      \
        }                                                                                        \
        { int tn = (TT + 2 < Tn) ? TT + 2 : Tn - 1;                                              \
          PF = *(const unsigned long long*)(preP + (size_t)tn * (Bn * Hn)); }                    \
    }

    for (int t = 0; t < Tn; t += 2) {
        REC_STEP(t, pfA, false)
        REC_STEP((t + 1), pfB, (t + 1 == Tn - 1))
    }
#undef REC_STEP
#undef POLL8
#undef PACK2
#undef CHK4
}

// ---------------- final readout ----------------
__global__ __launch_bounds__(64) void readout_k(const float* __restrict__ hfin,
                                                const float* __restrict__ Who1,
                                                const float* __restrict__ bho1,
                                                float* __restrict__ out) {
    int b = blockIdx.x;
    __shared__ float hv[Hn];
    int tid = threadIdx.x;
    for (int i = tid; i < Hn; i += 64) hv[i] = hfin[(size_t)b * Hn + i];
    __syncthreads();
    if (tid < OUTn) {
        float acc = bho1[tid];
        const float* wrow = Who1 + (size_t)tid * Hn;
#pragma unroll 8
        for (int i = 0; i < Hn; ++i) acc += wrow[i] * hv[i];
        out[b * OUTn + tid] = acc;
    }
}

extern "C" void kernel_launch(void* const* d_in, const int* in_sizes, int n_in,
                              void* d_out, int out_size, void* d_ws, size_t ws_size,
                              hipStream_t stream) {
    const float* inputs = (const float*)d_in[0];
    const float* b_d    = (const float*)d_in[1];
    const float* W_emb  = (const float*)d_in[2];
    const float* b_emb  = (const float*)d_in[3];
    const float* W_ih0  = (const float*)d_in[4];
    const float* b_ih0  = (const float*)d_in[5];
    const float* W_hh0  = (const float*)d_in[6];
    const float* b_hh0  = (const float*)d_in[7];
    const float* W_ho0  = (const float*)d_in[8];
    const float* b_ho0  = (const float*)d_in[9];
    const float* W_ih1  = (const float*)d_in[10];
    const float* b_ih1  = (const float*)d_in[11];
    const float* W_hh1  = (const float*)d_in[12];
    const float* b_hh1  = (const float*)d_in[13];
    const float* W_ho1  = (const float*)d_in[14];
    const float* b_ho1  = (const float*)d_in[15];

    char* ws = (char*)d_ws;
    size_t off = 0;
    auto alloc = [&](size_t bytes) {
        void* p = ws + off;
        off += (bytes + 255) & ~(size_t)255;
        return p;
    };
    unsigned short* B    = (unsigned short*)alloc(134217728); // resident [T,B,H] bf16
    unsigned short* Hf   = (unsigned short*)alloc(67108864);  // half-T bounce
    unsigned short* inb  = (unsigned short*)alloc(8388608);
    unsigned short* Wemb = (unsigned short*)alloc(32768);
    unsigned short* Wih0 = (unsigned short*)alloc(524288);
    unsigned short* Whh0 = (unsigned short*)alloc(524288);
    unsigned short* Who0 = (unsigned short*)alloc(524288);
    unsigned short* Wih1 = (unsigned short*)alloc(524288);
    unsigned short* Whh1 = (unsigned short*)alloc(524288);
    float* bias0 = (float*)alloc(2048);
    float* bias1 = (float*)alloc(2048);
    float* piB   = (float*)alloc(131072);
    unsigned int* ex = (unsigned int*)alloc(524288);          // [2][8][16][512] u32
    float* hfin = (float*)alloc(262144);
    (void)ws_size; (void)in_sizes; (void)n_in; (void)out_size;

    unsigned short* B_hi = B + (size_t)512 * Bn * Hn;
    const size_t halfBytes = 67108864;
    const int Mh = 512 * Bn;

    hipMemsetAsync(ex, 0, 524288, stream);
    cvt_k<<<4096, 256, 0, stream>>>(inputs, inb, 1048576);
    cvt_k<<<16,   256, 0, stream>>>(W_emb, Wemb, 4096);
    cvt_k<<<256,  256, 0, stream>>>(W_ih0, Wih0, 65536);
    cvt_k<<<256,  256, 0, stream>>>(W_hh0, Whh0, 65536);
    cvt_k<<<256,  256, 0, stream>>>(W_ho0, Who0, 65536);
    cvt_k<<<256,  256, 0, stream>>>(W_ih1, Wih1, 65536);
    cvt_k<<<256,  256, 0, stream>>>(W_hh1, Whh1, 65536);
    prep_small<<<1, 512, 0, stream>>>(b_d, b_ih0, b_hh0, b_ih1, b_hh1, piB, bias0, bias1);

    // ---- layer 0 ----
    gemm_bt<<<4096, 256, 0, stream>>>(inb, Wemb, B, b_emb, Tn * Bn, Hn, INn);    // B = x
    filt_k<<<dim3(8, 4, 128), 256, 0, stream>>>(B, piB, Hf, 512);
    gemm_bt<<<2048, 256, 0, stream>>>(Hf, Wih0, B_hi, bias0, Mh, Hn, Hn);        // B_hi = pre0_hi
    filt_k<<<dim3(8, 4, 128), 256, 0, stream>>>(B, piB, Hf, 0);
    gemm_bt<<<2048, 256, 0, stream>>>(Hf, Wih0, B, bias0, Mh, Hn, Hn);           // B_lo = pre0_lo
    rec15_k<<<64, 256, 0, stream>>>(Whh0, B, B, nullptr, ex, 0);                 // B = hs0 (in place)
    gemm_bt<<<2048, 256, 0, stream>>>(B_hi, Who0, Hf, b_ho0, Mh, Hn, Hn);
    hipMemcpyAsync(B_hi, Hf, halfBytes, hipMemcpyDeviceToDevice, stream);
    gemm_bt<<<2048, 256, 0, stream>>>(B, Who0, Hf, b_ho0, Mh, Hn, Hn);
    hipMemcpyAsync(B, Hf, halfBytes, hipMemcpyDeviceToDevice, stream);           // B = y0
    // ---- layer 1 ----
    filt_k<<<dim3(8, 4, 128), 256, 0, stream>>>(B, piB, Hf, 512);
    gemm_bt<<<2048, 256, 0, stream>>>(Hf, Wih1, B_hi, bias1, Mh, Hn, Hn);        // B_hi = pre1_hi
    filt_k<<<dim3(8, 4, 128), 256, 0, stream>>>(B, piB, Hf, 0);
    gemm_bt<<<2048, 256, 0, stream>>>(Hf, Wih1, B, bias1, Mh, Hn, Hn);           // B_lo = pre1_lo
    rec15_k<<<64, 256, 0, stream>>>(Whh1, B, nullptr, hfin, ex, 1024);
    readout_k<<<128, 64, 0, stream>>>(hfin, W_ho1, b_ho1, (float*)d_out);
}